// Round 8
// baseline (353.348 us; speedup 1.0000x reference)
//
#include <hip/hip_runtime.h>

// Attention_22325240004782 — additive attention. B=64, L=196, D=2048, A=1024.
// R8: af->bf16 conversion FUSED into GEMM (A reg-staged fp32, cvt, swizzled
// ds_write; T14 issue-early/write-late). B path = R6's proven gload_lds+LDS.
// 3 barriers/tile. conv pass eliminated; wsum reads fp32 af.

typedef unsigned short u16;
typedef u16 u16x8 __attribute__((ext_vector_type(8)));
typedef __bf16 bf16x8 __attribute__((ext_vector_type(8)));
typedef float f32x4 __attribute__((ext_vector_type(4)));

#define B_ 64
#define L_ 196
#define D_ 2048
#define A_ 1024
#define M_ (B_ * L_)  // 12544 = 49 * 256

__device__ __forceinline__ u16 f2bf(float x) {
  unsigned u = __float_as_uint(x);
  unsigned r = (u + 0x7fffu + ((u >> 16) & 1u)) >> 16;  // RNE
  return (u16)r;
}

__device__ __forceinline__ float tanh_fast(float x) {
  float e = __expf(2.0f * x);
  return 1.0f - 2.0f / (e + 1.0f);
}

__device__ __forceinline__ void gload_lds16(const void* g, void* l) {
  __builtin_amdgcn_global_load_lds(
      (const __attribute__((address_space(1))) void*)g,
      (__attribute__((address_space(3))) void*)l, 16, 0, 0);
}

// ---- fused prep: [0,256) ph split-K | [256,2304) W_att transpose ----
__global__ __launch_bounds__(256) void prep_k(
    const float* __restrict__ W, u16* __restrict__ WT,
    const float* __restrict__ h, const float* __restrict__ Wh,
    float* __restrict__ ph) {
  __shared__ float smem[2112];
  const int bid = blockIdx.x;
  const int t = threadIdx.x;
  if (bid < 256) {  // ph split-K (256-iter inner loop, atomics)
    const int ag = bid & 3, bg = (bid >> 2) & 7, dc = bid >> 5;
    const int d0 = dc * 256;
    for (int i = t; i < 2048; i += 256)
      smem[i] = h[(size_t)(bg * 8 + (i >> 8)) * D_ + d0 + (i & 255)];
    __syncthreads();
    const int a = ag * 256 + t;
    float acc[8] = {};
#pragma unroll 8
    for (int d = 0; d < 256; ++d) {
      float wv = Wh[(size_t)(d0 + d) * A_ + a];
#pragma unroll
      for (int bb = 0; bb < 8; ++bb) acc[bb] += smem[bb * 256 + d] * wv;
    }
#pragma unroll
    for (int bb = 0; bb < 8; ++bb)
      atomicAdd(&ph[(size_t)(bg * 8 + bb) * A_ + a], acc[bb]);
  } else {  // W_att [D][A] -> WT [A][D] bf16
    const int tb = bid - 256;
    const int n0 = (tb & 31) * 32, k0 = (tb >> 5) * 32;
    const int tx = t & 31, ty = t >> 5;
    float (*tt)[33] = (float (*)[33])smem;
#pragma unroll
    for (int i = 0; i < 4; ++i)
      tt[ty + i * 8][tx] = W[(size_t)(k0 + ty + i * 8) * A_ + n0 + tx];
    __syncthreads();
#pragma unroll
    for (int i = 0; i < 4; ++i)
      WT[(size_t)(n0 + ty + i * 8) * D_ + k0 + tx] = f2bf(tt[tx][ty + i * 8]);
  }
}

// ==== 256x256x(BK=64) GEMM, fused fp32->bf16 A-staging + tanh-score epi ====
// 512 thr = 8 waves (2M x 4N). A: fp32 global -> regs (issue at tile start)
// -> cvt -> swizzled ds_write (one phase later). B: gload_lds, pre-swizzled
// source (R6 verbatim). 3 barriers/tile; tile-end vmcnt(0) hits only old DMA.
__global__ __launch_bounds__(512, 2) void gemm8_k(
    const float* __restrict__ af, const u16* __restrict__ WT,
    const float* __restrict__ ph, const float* __restrict__ batt,
    const float* __restrict__ bh, const float* __restrict__ walpha,
    float* __restrict__ scores4) {
  __shared__ __align__(16) u16 As[2][2][8192];
  __shared__ __align__(16) u16 Bs[2][2][8192];
  const int tid = threadIdx.x;
  const int lane = tid & 63;
  const int wid = tid >> 6;
  const int wr = wid >> 2;   // 0..1 (M)
  const int wc = wid & 3;    // 0..3 (N)
  const int wchalf = wc >> 1, wcl = wc & 1;
  const int fr = lane & 15, fq = lane >> 4;

  // bijective XCD remap: 196 blocks, q=24, r=4
  const int xcd = blockIdx.x & 7, idx = blockIdx.x >> 3;
  const int wg = (xcd < 4 ? xcd * 25 : 100 + (xcd - 4) * 24) + idx;
  const int m0 = (wg >> 2) * 256;
  const int n0 = (wg & 3) * 256;

  // ---- A reg-staging maps: 2048 chunks of 8 elems; 4 per thread ----
  // chunk c: half hh=c>>10, row=(c&1023)>>3, cc=(c&1023)&7.
  // LDS dest (u16 idx, matches reader's laneA swizzle exactly):
  //   ((row>>4)*2+(cc>>2))*512 + (row&15)*32 + (((cc&3)*8) ^ ((row&8)<<1))
  const float* aSrc[4];
  int aHh[4], aLds[4];
#pragma unroll
  for (int r = 0; r < 4; ++r) {
    const int c = r * 512 + tid;
    const int hh = c >> 10, cl = c & 1023;
    const int row = cl >> 3, cc = cl & 7;
    aHh[r] = hh;
    aSrc[r] = af + (size_t)(m0 + hh * 128 + row) * D_ + cc * 8;
    aLds[r] = ((row >> 4) * 2 + (cc >> 2)) * 512 + (row & 15) * 32 +
              (((cc & 3) * 8) ^ ((row & 8) << 1));
  }

  // ---- B staging geometry (pre-swizzled global source, linear LDS dest) ----
  int rowc[2], colc[2];
#pragma unroll
  for (int r = 0; r < 2; ++r) {
    int c = r * 512 + tid;
    int s = c >> 6, cw = c & 63;
    rowc[r] = (s >> 1) * 16 + (cw >> 2);
    colc[r] = (s & 1) * 32 + ((((cw & 3) * 16) ^ (((cw >> 5) & 1) * 32)) >> 1);
  }
  const u16* srcB[2][2];
#pragma unroll
  for (int hh = 0; hh < 2; ++hh)
#pragma unroll
    for (int r = 0; r < 2; ++r)
      srcB[hh][r] = WT + (size_t)(n0 + hh * 128 + rowc[r]) * D_ + colc[r];

  // swizzled lane byte offset for ds_read_b128 fragment reads
  const int laneA = (lane & 15) * 64 + (((lane >> 4) * 16) ^ ((lane & 8) << 2));

  f32x4 acc[8][4] = {};
  u16x8 areg[4][2], breg[4][2];

#define STG_B2(BUF, H, KT)                                                   \
  do {                                                                       \
    gload_lds16(srcB[H][0] + (size_t)(KT) * 64, &Bs[BUF][H][wid * 512]);     \
    gload_lds16(srcB[H][1] + (size_t)(KT) * 64, &Bs[BUF][H][4096 + wid * 512]); \
  } while (0)
#define LDA_HALF(BF, MH)                                                     \
  do {                                                                       \
    _Pragma("unroll") for (int q = 0; q < 4; ++q) {                          \
      areg[q][0] = *(const u16x8*)&As[BF][wr][((((MH)*4 + q) * 2 + 0) * 1024 + laneA) >> 1]; \
      areg[q][1] = *(const u16x8*)&As[BF][wr][((((MH)*4 + q) * 2 + 1) * 1024 + laneA) >> 1]; \
    }                                                                        \
  } while (0)
#define LDB_PAIR(BF, NQ)                                                     \
  do {                                                                       \
    _Pragma("unroll") for (int nn = 0; nn < 2; ++nn) {                       \
      breg[(NQ)*2 + nn][0] = *(const u16x8*)&Bs[BF][wchalf][(((wcl * 4 + (NQ)*2 + nn) * 2 + 0) * 1024 + laneA) >> 1]; \
      breg[(NQ)*2 + nn][1] = *(const u16x8*)&Bs[BF][wchalf][(((wcl * 4 + (NQ)*2 + nn) * 2 + 1) * 1024 + laneA) >> 1]; \
    }                                                                        \
  } while (0)
#define MM_QUAD(MH, NQ)                                                      \
  do {                                                                       \
    _Pragma("unroll") for (int q = 0; q < 4; ++q)                            \
    _Pragma("unroll") for (int nn = 0; nn < 2; ++nn)                         \
    _Pragma("unroll") for (int kh = 0; kh < 2; ++kh)                         \
      acc[(MH)*4 + q][(NQ)*2 + nn] = __builtin_amdgcn_mfma_f32_16x16x32_bf16( \
          __builtin_bit_cast(bf16x8, areg[q][kh]),                           \
          __builtin_bit_cast(bf16x8, breg[(NQ)*2 + nn][kh]),                 \
          acc[(MH)*4 + q][(NQ)*2 + nn], 0, 0, 0);                            \
  } while (0)
#define LGKM_BAR()                                                           \
  do {                                                                       \
    asm volatile("s_waitcnt lgkmcnt(0)" ::: "memory");                       \
    __builtin_amdgcn_s_barrier();                                            \
  } while (0)
// Tile t (BF=t&1). Hazard audit (3 barriers):
//  - STG_B/A-write -> buf^1: its readers closed at t-1's end barrier.
//  - ACVT's auto vmcnt waits only the 8 A-loads (B DMA issued after -> counted).
//  - end vmcnt(0): B(t+1) DMA is ~2 windows old -> free; guarantees Bs[BF^1]
//    valid for t+1's LDB. lgkm0+barrier publishes A-writes.
#define TILE(BF, T, MODE)                                                    \
  do {                                                                       \
    float4 a4[4][2];                                                         \
    if ((MODE) == 0) {                                                       \
      _Pragma("unroll") for (int r = 0; r < 4; ++r) {                        \
        a4[r][0] = *(const float4*)(aSrc[r] + (size_t)((T) + 1) * 64);       \
        a4[r][1] = *(const float4*)(aSrc[r] + (size_t)((T) + 1) * 64 + 4);   \
      }                                                                      \
      STG_B2((BF) ^ 1, 0, (T) + 1);                                         \
      STG_B2((BF) ^ 1, 1, (T) + 1);                                         \
    }                                                                        \
    LDA_HALF(BF, 0); LDB_PAIR(BF, 0); LDB_PAIR(BF, 1);                       \
    LGKM_BAR();                                                              \
    __builtin_amdgcn_s_setprio(1);                                           \
    MM_QUAD(0, 0); MM_QUAD(0, 1);                                            \
    __builtin_amdgcn_s_setprio(0);                                           \
    LDA_HALF(BF, 1);                                                         \
    if ((MODE) == 0) {                                                       \
      _Pragma("unroll") for (int r = 0; r < 4; ++r) {                        \
        u16x8 p;                                                             \
        p[0] = f2bf(a4[r][0].x); p[1] = f2bf(a4[r][0].y);                    \
        p[2] = f2bf(a4[r][0].z); p[3] = f2bf(a4[r][0].w);                    \
        p[4] = f2bf(a4[r][1].x); p[5] = f2bf(a4[r][1].y);                    \
        p[6] = f2bf(a4[r][1].z); p[7] = f2bf(a4[r][1].w);                    \
        *(u16x8*)&As[(BF) ^ 1][aHh[r]][aLds[r]] = p;                         \
      }                                                                      \
    }                                                                        \
    LGKM_BAR();                                                              \
    __builtin_amdgcn_s_setprio(1);                                           \
    MM_QUAD(1, 0); MM_QUAD(1, 1);                                            \
    __builtin_amdgcn_s_setprio(0);                                           \
    if ((MODE) == 0) {                                                       \
      asm volatile("s_waitcnt vmcnt(0)" ::: "memory");                       \
      LGKM_BAR();                                                            \
    }                                                                        \
  } while (0)

  // prologue: A(0) load->cvt->write, B(0) DMA; full drain once.
  {
    float4 a4[4][2];
#pragma unroll
    for (int r = 0; r < 4; ++r) {
      a4[r][0] = *(const float4*)(aSrc[r]);
      a4[r][1] = *(const float4*)(aSrc[r] + 4);
    }
    STG_B2(0, 0, 0);
    STG_B2(0, 1, 0);
#pragma unroll
    for (int r = 0; r < 4; ++r) {
      u16x8 p;
      p[0] = f2bf(a4[r][0].x); p[1] = f2bf(a4[r][0].y);
      p[2] = f2bf(a4[r][0].z); p[3] = f2bf(a4[r][0].w);
      p[4] = f2bf(a4[r][1].x); p[5] = f2bf(a4[r][1].y);
      p[6] = f2bf(a4[r][1].z); p[7] = f2bf(a4[r][1].w);
      *(u16x8*)&As[0][aHh[r]][aLds[r]] = p;
    }
    asm volatile("s_waitcnt vmcnt(0) lgkmcnt(0)" ::: "memory");
    __builtin_amdgcn_s_barrier();
  }

#pragma unroll 1
  for (int it = 0; it < 16; ++it) {
    TILE(0, 2 * it, 0);
    if (it < 15) {
      TILE(1, 2 * it + 1, 0);
    } else {
      TILE(1, 31, 1);
    }
  }

  // ---- slim epilogue: hoisted invariants, <=3-batch ph select, LDS reduce ----
  const int gnb = n0 + wc * 64 + fr;
  float wa[4], bsv[4], p0[4], p1[4], p2[4];
  const int b0 = m0 / L_;
  const int s1 = (b0 + 1) * L_, s2 = (b0 + 2) * L_;
  const int b1 = (b0 + 1 > 63) ? 63 : b0 + 1;
  const int b2 = (b0 + 2 > 63) ? 63 : b0 + 2;
#pragma unroll
  for (int ni = 0; ni < 4; ++ni) {
    const int gn = gnb + ni * 16;
    wa[ni] = walpha[gn];
    bsv[ni] = batt[gn] + bh[gn];
    p0[ni] = ph[(size_t)b0 * A_ + gn];
    p1[ni] = ph[(size_t)b1 * A_ + gn];
    p2[ni] = ph[(size_t)b2 * A_ + gn];
  }
  __syncthreads();  // all tile reads done before reusing As as scratch
  float (*redp)[128][4] = (float (*)[128][4])As;
#pragma unroll
  for (int mi = 0; mi < 8; ++mi) {
#pragma unroll
    for (int rr = 0; rr < 4; ++rr) {
      const int lr = mi * 16 + fq * 4 + rr;
      const int gm = m0 + wr * 128 + lr;
      float sp = 0.f;
#pragma unroll
      for (int ni = 0; ni < 4; ++ni) {
        const float pv = (gm >= s2) ? p2[ni] : ((gm >= s1) ? p1[ni] : p0[ni]);
        const float p = acc[mi][ni][rr] + pv + bsv[ni];
        sp += tanh_fast(p) * wa[ni];
      }
      sp += __shfl_xor(sp, 1);
      sp += __shfl_xor(sp, 2);
      sp += __shfl_xor(sp, 4);
      sp += __shfl_xor(sp, 8);
      if (fr == 0) redp[wr][lr][wc] = sp;
    }
  }
  __syncthreads();
  if (tid < 256) {
    f32x4 v = ((const f32x4*)redp)[tid];
    scores4[(size_t)(n0 >> 8) * M_ + m0 + tid] = v[0] + v[1] + v[2] + v[3];
  }
}

// ---- fused softmax + weighted sum (fp32 af) ----
__global__ __launch_bounds__(256) void wsum_sm_k(const float* __restrict__ af,
                                                 const float* __restrict__ s4,
                                                 float* __restrict__ out) {
  __shared__ float wl[256];
  __shared__ f32x4 part[256];
  __shared__ float red[4];
  const int b = blockIdx.y;
  const int t = threadIdx.x;

  // softmax over L=196
  float s = -1e30f;
  if (t < L_) {
    const int i = b * L_ + t;
    s = s4[i] + s4[M_ + i] + s4[2 * M_ + i] + s4[3 * M_ + i];
  }
  float m = s;
#pragma unroll
  for (int o = 32; o; o >>= 1) m = fmaxf(m, __shfl_xor(m, o));
  if ((t & 63) == 0) red[t >> 6] = m;
  __syncthreads();
  m = fmaxf(fmaxf(red[0], red[1]), fmaxf(red[2], red[3]));
  float e = (t < L_) ? __expf(s - m) : 0.f;
  float sum = e;
#pragma unroll
  for (int o = 32; o; o >>= 1) sum += __shfl_xor(sum, o);
  __syncthreads();
  if ((t & 63) == 0) red[t >> 6] = sum;
  __syncthreads();
  sum = red[0] + red[1] + red[2] + red[3];
  const float w = e / sum;
  wl[t] = w;
  if (t < L_ && blockIdx.x == 0) out[(size_t)B_ * D_ + b * L_ + t] = w;
  __syncthreads();

  // weighted sum over L for 256 d4-columns (64 lanes x float4)
  const int lq = t >> 6;
  const int dl = t & 63;
  const int d4 = blockIdx.x * 64 + dl;  // 0..511 of float4 groups
  f32x4 acc = {0.f, 0.f, 0.f, 0.f};
  for (int l = lq * 49; l < lq * 49 + 49; ++l) {
    f32x4 v = *(const f32x4*)(af + (size_t)(b * L_ + l) * D_ + d4 * 4);
    acc += v * wl[l];
  }
  part[t] = acc;
  __syncthreads();
  if (t < 64) {
    f32x4 tot = part[t] + part[64 + t] + part[128 + t] + part[192 + t];
    *(f32x4*)(out + (size_t)b * D_ + d4 * 4) = tot;
  }
}

extern "C" void kernel_launch(void* const* d_in, const int* in_sizes, int n_in,
                              void* d_out, int out_size, void* d_ws, size_t ws_size,
                              hipStream_t stream) {
  const float* af    = (const float*)d_in[0];
  const float* h     = (const float*)d_in[1];
  const float* W_att = (const float*)d_in[2];
  const float* b_att = (const float*)d_in[3];
  const float* W_h   = (const float*)d_in[4];
  const float* b_h   = (const float*)d_in[5];
  const float* w_al  = (const float*)d_in[6];
  float* out = (float*)d_out;
  char* ws = (char*)d_ws;

  u16* WT        = (u16*)ws;                       // 4 MB
  float* ph      = (float*)(ws + 0x400000);        // 256 KB
  float* scores4 = (float*)(ws + 0x440000);        // 4 x 12544 fp32 = 200 KB

  hipMemsetAsync(ph, 0, 256u << 10, stream);
  prep_k<<<2304, 256, 0, stream>>>(W_att, WT, h, W_h, ph);
  gemm8_k<<<196, 512, 0, stream>>>(af, WT, ph, b_att, b_h, w_al, scores4);
  wsum_sm_k<<<dim3(8, 64), 256, 0, stream>>>(af, scores4, out);
}

// Round 9
// 130.672 us; speedup vs baseline: 2.7041x; 2.7041x over previous
//
#include <hip/hip_runtime.h>

// Attention_22325240004782 — additive attention. B=64, L=196, D=2048, A=1024.
// R9: R6 schedule verbatim, geometry BM256xBN64xBK64 -> 784 blocks (full
// machine), 80 KiB LDS -> 2 blocks/CU co-residency, low reg pressure.
// vmcnt(3) FIFO (5 loads/tile). Epilogue writes per-n-group score partials.

typedef unsigned short u16;
typedef u16 u16x8 __attribute__((ext_vector_type(8)));
typedef __bf16 bf16x8 __attribute__((ext_vector_type(8)));
typedef float f32x4 __attribute__((ext_vector_type(4)));

#define B_ 64
#define L_ 196
#define D_ 2048
#define A_ 1024
#define M_ (B_ * L_)  // 12544 = 49 * 256

__device__ __forceinline__ u16 f2bf(float x) {
  unsigned u = __float_as_uint(x);
  unsigned r = (u + 0x7fffu + ((u >> 16) & 1u)) >> 16;  // RNE
  return (u16)r;
}

__device__ __forceinline__ float tanh_fast(float x) {
  float e = __expf(2.0f * x);
  return 1.0f - 2.0f / (e + 1.0f);
}

__device__ __forceinline__ void gload_lds16(const void* g, void* l) {
  __builtin_amdgcn_global_load_lds(
      (const __attribute__((address_space(1))) void*)g,
      (__attribute__((address_space(3))) void*)l, 16, 0, 0);
}

// ---- fused prep: [0,256) ph split-K | [256,2304) W_att transpose |
//                  [2304,4352) af->bf16 ----
__global__ __launch_bounds__(256) void prep_k(
    const float* __restrict__ af, u16* __restrict__ afb,
    const float* __restrict__ W, u16* __restrict__ WT,
    const float* __restrict__ h, const float* __restrict__ Wh,
    float* __restrict__ ph) {
  __shared__ float smem[2112];
  const int bid = blockIdx.x;
  const int t = threadIdx.x;
  if (bid < 256) {  // ph split-K (256-iter inner loop, atomics)
    const int ag = bid & 3, bg = (bid >> 2) & 7, dc = bid >> 5;
    const int d0 = dc * 256;
    for (int i = t; i < 2048; i += 256)
      smem[i] = h[(size_t)(bg * 8 + (i >> 8)) * D_ + d0 + (i & 255)];
    __syncthreads();
    const int a = ag * 256 + t;
    float acc[8] = {};
#pragma unroll 8
    for (int d = 0; d < 256; ++d) {
      float wv = Wh[(size_t)(d0 + d) * A_ + a];
#pragma unroll
      for (int bb = 0; bb < 8; ++bb) acc[bb] += smem[bb * 256 + d] * wv;
    }
#pragma unroll
    for (int bb = 0; bb < 8; ++bb)
      atomicAdd(&ph[(size_t)(bg * 8 + bb) * A_ + a], acc[bb]);
  } else if (bid < 2304) {  // W_att [D][A] -> WT [A][D] bf16
    const int tb = bid - 256;
    const int n0 = (tb & 31) * 32, k0 = (tb >> 5) * 32;
    const int tx = t & 31, ty = t >> 5;
    float (*tt)[33] = (float (*)[33])smem;
#pragma unroll
    for (int i = 0; i < 4; ++i)
      tt[ty + i * 8][tx] = W[(size_t)(k0 + ty + i * 8) * A_ + n0 + tx];
    __syncthreads();
#pragma unroll
    for (int i = 0; i < 4; ++i)
      WT[(size_t)(n0 + ty + i * 8) * D_ + k0 + tx] = f2bf(tt[tx][ty + i * 8]);
  } else {  // af fp32 -> bf16 (BW-bound, backfills)
    const int cb = bid - 2304;
    const size_t n = (size_t)M_ * D_;
    for (size_t e = ((size_t)cb * 256 + t) * 8; e < n;
         e += (size_t)2048 * 256 * 8) {
      float4 v0 = *(const float4*)(af + e);
      float4 v1 = *(const float4*)(af + e + 4);
      u16x8 p;
      p[0] = f2bf(v0.x); p[1] = f2bf(v0.y); p[2] = f2bf(v0.z); p[3] = f2bf(v0.w);
      p[4] = f2bf(v1.x); p[5] = f2bf(v1.y); p[6] = f2bf(v1.z); p[7] = f2bf(v1.w);
      *(u16x8*)(afb + e) = p;
    }
  }
}

// ==== 256x64x(BK=64) GEMM, R6 schedule, 2 blocks/CU ====
// 512 thr = 8 waves, each owns 32 output rows x 64 cols. A: 2x[128][64] LDS
// halves (as R6). B: one [64][64] tile (1 gload/thread). st_16x32 swizzle.
// Per tile 5 loads staged; end-of-tile vmcnt(3) retires next tile's 5.
__global__ __launch_bounds__(512, 4) void gemm8_k(
    const u16* __restrict__ afb, const u16* __restrict__ WT,
    const float* __restrict__ ph, const float* __restrict__ batt,
    const float* __restrict__ bh, const float* __restrict__ walpha,
    float* __restrict__ scores16) {
  __shared__ __align__(16) u16 As[2][2][8192];
  __shared__ __align__(16) u16 Bs[2][4096];
  const int tid = threadIdx.x;
  const int lane = tid & 63;
  const int wid = tid >> 6;
  const int fr = lane & 15, fq = lane >> 4;

  // XCD remap: 784 blocks, 784%8==0 -> simple bijective chunk map
  const int wg = (blockIdx.x & 7) * 98 + (blockIdx.x >> 3);
  const int m0 = (wg >> 4) * 256;
  const int n0 = (wg & 15) * 64;

  // ---- A staging geometry (pre-swizzled source, linear LDS dest; R6) ----
  int rowc[2], colc[2];
#pragma unroll
  for (int r = 0; r < 2; ++r) {
    int c = r * 512 + tid;
    int s = c >> 6, cw = c & 63;
    rowc[r] = (s >> 1) * 16 + (cw >> 2);
    colc[r] = (s & 1) * 32 + ((((cw & 3) * 16) ^ (((cw >> 5) & 1) * 32)) >> 1);
  }
  const u16* srcA[2][2];
#pragma unroll
  for (int hh = 0; hh < 2; ++hh)
#pragma unroll
    for (int r = 0; r < 2; ++r)
      srcA[hh][r] = afb + (size_t)(m0 + hh * 128 + rowc[r]) * D_ + colc[r];
  // B tile 64x64 = 512 chunks, 1 per thread (c = tid, s = c>>6 in 0..7)
  const u16* srcB = WT + (size_t)(n0 + rowc[0]) * D_ + colc[0];

  // swizzled lane byte offset for ds_read_b128 fragment reads
  const int laneA = (lane & 15) * 64 + (((lane >> 4) * 16) ^ ((lane & 8) << 2));
  const int ahh = wid >> 2;   // which 128-row LDS half
  const int arow2 = (wid & 3) * 2;  // subtile row base within half

  f32x4 acc[2][4] = {};
  u16x8 areg[2][2], breg[4][2];

#define STG_A(BUF, H, KT)                                                    \
  do {                                                                       \
    gload_lds16(srcA[H][0] + (size_t)(KT) * 64, &As[BUF][H][wid * 512]);     \
    gload_lds16(srcA[H][1] + (size_t)(KT) * 64, &As[BUF][H][4096 + wid * 512]); \
  } while (0)
#define STG_B(BUF, KT)                                                       \
  gload_lds16(srcB + (size_t)(KT) * 64, &Bs[BUF][wid * 512])
#define LDA_MI(BF, MI)                                                       \
  do {                                                                       \
    areg[MI][0] = *(const u16x8*)&As[BF][ahh][(((arow2 + (MI)) * 2 + 0) * 1024 + laneA) >> 1]; \
    areg[MI][1] = *(const u16x8*)&As[BF][ahh][(((arow2 + (MI)) * 2 + 1) * 1024 + laneA) >> 1]; \
  } while (0)
#define LDB_ALL(BF)                                                          \
  do {                                                                       \
    _Pragma("unroll") for (int ni = 0; ni < 4; ++ni)                         \
    _Pragma("unroll") for (int kh = 0; kh < 2; ++kh)                         \
      breg[ni][kh] = *(const u16x8*)&Bs[BF][((ni * 2 + kh) * 1024 + laneA) >> 1]; \
  } while (0)
#define MM(MI)                                                               \
  do {                                                                       \
    _Pragma("unroll") for (int ni = 0; ni < 4; ++ni)                         \
    _Pragma("unroll") for (int kh = 0; kh < 2; ++kh)                         \
      acc[MI][ni] = __builtin_amdgcn_mfma_f32_16x16x32_bf16(                 \
          __builtin_bit_cast(bf16x8, areg[MI][kh]),                          \
          __builtin_bit_cast(bf16x8, breg[ni][kh]), acc[MI][ni], 0, 0, 0);   \
  } while (0)
#define PH_PRE()                                                             \
  do {                                                                       \
    __builtin_amdgcn_s_barrier();                                            \
    asm volatile("s_waitcnt lgkmcnt(0)" ::: "memory");                       \
    __builtin_amdgcn_s_setprio(1);                                           \
  } while (0)
#define PH_POST()                                                            \
  do {                                                                       \
    __builtin_amdgcn_s_setprio(0);                                           \
    __builtin_amdgcn_s_barrier();                                            \
  } while (0)
// FIFO invariant: enter tile t with t's data retired and {t+1.B, t+1.A0}
// (3 loads) outstanding; in-tile issue t+1.A1 (2), t+2.B (1), t+2.A0 (2);
// end vmcnt(3) retires oldest 5 = ALL of tile t+1's data.
#define KTILE(BF, T, MODE)                                                   \
  do {                                                                       \
    LDA_MI(BF, 0); LDB_ALL(BF);                                              \
    if ((MODE) <= 1) STG_A((BF) ^ 1, 1, (T) + 1);                            \
    PH_PRE(); MM(0); PH_POST();                                              \
    LDA_MI(BF, 1);                                                           \
    if ((MODE) == 0) { STG_B(BF, (T) + 2); STG_A(BF, 0, (T) + 2); }          \
    PH_PRE(); MM(1);                                                         \
    __builtin_amdgcn_s_setprio(0);                                           \
    if ((MODE) == 0) asm volatile("s_waitcnt vmcnt(3)" ::: "memory");        \
    if ((MODE) == 1) asm volatile("s_waitcnt vmcnt(0)" ::: "memory");        \
    if ((MODE) <= 1) __builtin_amdgcn_s_barrier();                           \
  } while (0)

  // prologue: tile0 {B,A0,A1} (5 loads) + tile1 {B,A0} (3 loads)
  STG_B(0, 0); STG_A(0, 0, 0); STG_A(0, 1, 0);
  STG_B(1, 1); STG_A(1, 0, 1);
  asm volatile("s_waitcnt vmcnt(3)" ::: "memory");
  __builtin_amdgcn_s_barrier();

#pragma unroll 1
  for (int it = 0; it < 15; ++it) {
    KTILE(0, 2 * it, 0);
    KTILE(1, 2 * it + 1, 0);
  }
  KTILE(0, 30, 1);
  KTILE(1, 31, 2);

  // ---- epilogue: each wave owns 32 distinct rows -> direct global write ----
  const int gnb = n0 + fr;
  float wa[4], bsv[4], p0[4], p1[4], p2[4];
  const int b0 = m0 / L_;
  const int s1 = (b0 + 1) * L_, s2 = (b0 + 2) * L_;
  const int b1 = (b0 + 1 > 63) ? 63 : b0 + 1;
  const int b2 = (b0 + 2 > 63) ? 63 : b0 + 2;
#pragma unroll
  for (int ni = 0; ni < 4; ++ni) {
    const int gn = gnb + ni * 16;
    wa[ni] = walpha[gn];
    bsv[ni] = batt[gn] + bh[gn];
    p0[ni] = ph[(size_t)b0 * A_ + gn];
    p1[ni] = ph[(size_t)b1 * A_ + gn];
    p2[ni] = ph[(size_t)b2 * A_ + gn];
  }
  float* sout = scores16 + (size_t)(wg & 15) * M_;
#pragma unroll
  for (int mi = 0; mi < 2; ++mi) {
#pragma unroll
    for (int rr = 0; rr < 4; ++rr) {
      const int gm = m0 + wid * 32 + mi * 16 + fq * 4 + rr;
      float sp = 0.f;
#pragma unroll
      for (int ni = 0; ni < 4; ++ni) {
        const float pv = (gm >= s2) ? p2[ni] : ((gm >= s1) ? p1[ni] : p0[ni]);
        const float p = acc[mi][ni][rr] + pv + bsv[ni];
        sp += tanh_fast(p) * wa[ni];
      }
      sp += __shfl_xor(sp, 1);
      sp += __shfl_xor(sp, 2);
      sp += __shfl_xor(sp, 4);
      sp += __shfl_xor(sp, 8);
      if (fr == 0) sout[gm] = sp;
    }
  }
}

// ---- fused softmax (16 partials) + weighted sum (bf16 af) ----
__global__ __launch_bounds__(256) void wsum_sm_k(const u16* __restrict__ afb,
                                                 const float* __restrict__ s16,
                                                 float* __restrict__ out) {
  __shared__ float wl[256];
  __shared__ float part[256][8];
  __shared__ float red[4];
  const int b = blockIdx.y;
  const int t = threadIdx.x;

  float s = -1e30f;
  if (t < L_) {
    const int i = b * L_ + t;
    s = 0.f;
#pragma unroll
    for (int g = 0; g < 16; ++g) s += s16[(size_t)g * M_ + i];
  }
  float m = s;
#pragma unroll
  for (int o = 32; o; o >>= 1) m = fmaxf(m, __shfl_xor(m, o));
  if ((t & 63) == 0) red[t >> 6] = m;
  __syncthreads();
  m = fmaxf(fmaxf(red[0], red[1]), fmaxf(red[2], red[3]));
  float e = (t < L_) ? __expf(s - m) : 0.f;
  float sum = e;
#pragma unroll
  for (int o = 32; o; o >>= 1) sum += __shfl_xor(sum, o);
  __syncthreads();
  if ((t & 63) == 0) red[t >> 6] = sum;
  __syncthreads();
  sum = red[0] + red[1] + red[2] + red[3];
  const float w = e / sum;
  wl[t] = w;
  if (t < L_ && blockIdx.x == 0) out[(size_t)B_ * D_ + b * L_ + t] = w;
  __syncthreads();

  const int lq = t >> 6;
  const int dl = t & 63;
  const int d8 = blockIdx.x * 64 + dl;
  float acc[8] = {};
  for (int l = lq * 49; l < lq * 49 + 49; ++l) {
    u16x8 v = *(const u16x8*)(afb + (size_t)(b * L_ + l) * D_ + d8 * 8);
    float ww = wl[l];
#pragma unroll
    for (int j = 0; j < 8; ++j)
      acc[j] += ww * __uint_as_float((unsigned)v[j] << 16);
  }
#pragma unroll
  for (int j = 0; j < 8; ++j) part[t][j] = acc[j];
  __syncthreads();
  if (t < 64) {
    float4 o0, o1;
    o0.x = part[dl][0] + part[64 + dl][0] + part[128 + dl][0] + part[192 + dl][0];
    o0.y = part[dl][1] + part[64 + dl][1] + part[128 + dl][1] + part[192 + dl][1];
    o0.z = part[dl][2] + part[64 + dl][2] + part[128 + dl][2] + part[192 + dl][2];
    o0.w = part[dl][3] + part[64 + dl][3] + part[128 + dl][3] + part[192 + dl][3];
    o1.x = part[dl][4] + part[64 + dl][4] + part[128 + dl][4] + part[192 + dl][4];
    o1.y = part[dl][5] + part[64 + dl][5] + part[128 + dl][5] + part[192 + dl][5];
    o1.z = part[dl][6] + part[64 + dl][6] + part[128 + dl][6] + part[192 + dl][6];
    o1.w = part[dl][7] + part[64 + dl][7] + part[128 + dl][7] + part[192 + dl][7];
    *(float4*)(out + (size_t)b * D_ + d8 * 8) = o0;
    *(float4*)(out + (size_t)b * D_ + d8 * 8 + 4) = o1;
  }
}

extern "C" void kernel_launch(void* const* d_in, const int* in_sizes, int n_in,
                              void* d_out, int out_size, void* d_ws, size_t ws_size,
                              hipStream_t stream) {
  const float* af    = (const float*)d_in[0];
  const float* h     = (const float*)d_in[1];
  const float* W_att = (const float*)d_in[2];
  const float* b_att = (const float*)d_in[3];
  const float* W_h   = (const float*)d_in[4];
  const float* b_h   = (const float*)d_in[5];
  const float* w_al  = (const float*)d_in[6];
  float* out = (float*)d_out;
  char* ws = (char*)d_ws;

  u16* afb        = (u16*)ws;                      // 51.4 MB
  u16* WT         = (u16*)(ws + 0x3200000);        // 4 MB
  float* ph       = (float*)(ws + 0x3600000);      // 256 KB
  float* scores16 = (float*)(ws + 0x3640000);      // 16 x 12544 fp32 = 803 KB

  hipMemsetAsync(ph, 0, 256u << 10, stream);
  prep_k<<<4352, 256, 0, stream>>>(af, afb, W_att, WT, h, W_h, ph);
  gemm8_k<<<784, 512, 0, stream>>>(afb, WT, ph, b_att, b_h, w_al, scores16);
  wsum_sm_k<<<dim3(4, 64), 256, 0, stream>>>(afb, scores16, out);
}